// Round 9
// baseline (81.634 us; speedup 1.0000x reference)
//
#include <hip/hip_runtime.h>

#define BATCH 4
#define CIN 64
#define H 128
#define W 128
#define COUT 64
#define KK 9
#define HO 128
#define WO 128

typedef short bf16x8 __attribute__((ext_vector_type(8)));
typedef float f32x4 __attribute__((ext_vector_type(4)));

__device__ __forceinline__ unsigned short f2bf(float f) {
    unsigned u = __builtin_bit_cast(unsigned, f);
    u += 0x7FFFu + ((u >> 16) & 1u);          // RNE
    return (unsigned short)(u >> 16);
}
__device__ __forceinline__ float bflo(unsigned u) {   // low bf16 of dword
    return __builtin_bit_cast(float, u << 16);
}
__device__ __forceinline__ float bfhi(unsigned u) {   // high bf16 of dword
    return __builtin_bit_cast(float, u & 0xFFFF0000u);
}

// bilinear on one packed dword-column (2 channels), pack result to bf16x2
__device__ __forceinline__ unsigned bil_pack(unsigned u0, unsigned u1,
                                             unsigned u2, unsigned u3, f32x4 wv) {
    float lo = fmaf(wv[0], bflo(u0), fmaf(wv[1], bflo(u1),
               fmaf(wv[2], bflo(u2), wv[3] * bflo(u3))));
    float hi = fmaf(wv[0], bfhi(u0), fmaf(wv[1], bfhi(u1),
               fmaf(wv[2], bfhi(u2), wv[3] * bfhi(u3))));
    unsigned pk;
    asm("v_cvt_pk_bf16_f32 %0, %1, %2" : "=v"(pk) : "v"(lo), "v"(hi));
    return pk;
}

// Prep: blocks 0..1023 NCHW->NHWC bf16 transpose; 1024..1167 weight transpose
__global__ __launch_bounds__(256)
void prep(const float* __restrict__ x, const float* __restrict__ w,
          unsigned short* __restrict__ xn, unsigned short* __restrict__ wt2) {
    const int blk = blockIdx.x;
    const int tid = threadIdx.x;

    if (blk >= 1024) {
        int g = (blk - 1024) * 256 + tid;     // 0..36863
        int o = g / 576;
        int rem = g - o * 576;
        int k = rem >> 6, c = rem & 63;
        wt2[g] = f2bf(w[(o * 64 + c) * 9 + k]);
        return;
    }

    const int b = blk >> 8, oy = (blk >> 1) & 127, xh = blk & 1;

    __shared__ float T[64][65];
    const int px = tid & 63, cq = tid >> 6;
    const float* src = x + (((size_t)b * 64) << 14) + oy * 128 + xh * 64;
    #pragma unroll
    for (int j = 0; j < 16; ++j) {
        int c = cq * 16 + j;
        T[c][px] = src[((size_t)c << 14) + px];
    }
    __syncthreads();
    const int c2 = tid & 63, pq = tid >> 6;
    unsigned short* dst = xn + ((((size_t)b << 14) + oy * 128 + xh * 64) << 6) + c2;
    #pragma unroll
    for (int j = 0; j < 16; ++j) {
        int p = pq * 16 + j;
        dst[(size_t)p << 6] = f2bf(T[c2][p]);
    }
}

__global__ __launch_bounds__(256, 4)
void dcn_main(const unsigned short* __restrict__ xn, const unsigned short* __restrict__ wt2,
              const float* __restrict__ offs, const float* __restrict__ mask,
              const float* __restrict__ bias, float* __restrict__ out) {
    const int tid  = threadIdx.x;
    const int lane = tid & 63;
    const int wid  = tid >> 6;
    const int blk  = blockIdx.x;            // 0..1023 = b*256 + oy*2 + xh
    const int b    = blk >> 8;              // FIX (r8 bug: was blk>>9)
    const int oy   = (blk >> 1) & 127;
    const int xh   = blk & 1;
    const int px0  = xh * 64 + wid * 16;    // this wave's 16-px tile

    __shared__ int   DI[4][KK][16];
    __shared__ __align__(16) f32x4 DW[4][KK][16];

    // ---- per-wave descriptor compute: 144 descs over 64 lanes (no barrier) ----
    #pragma unroll
    for (int r = 0; r < 3; ++r) {
        int s = r * 64 + lane;
        if (s < 144) {
            int k = s >> 4, px = s & 15;
            int ox = px0 + px;
            int kh = k / 3, kw = k - kh * 3;

            float offy = offs[((b * 18 + 2 * k    ) * 128 + oy) * 128 + ox];
            float offx = offs[((b * 18 + 2 * k + 1) * 128 + oy) * 128 + ox];
            float m    = mask[((b * 9  + k        ) * 128 + oy) * 128 + ox];

            float py  = (float)(oy - 1 + kh) + offy;
            float pxf = (float)(ox - 1 + kw) + offx;
            float fy = floorf(py), fx = floorf(pxf);
            float ly = py - fy, lx = pxf - fx;
            int y0 = (int)fy, x0 = (int)fx;
            int y1 = y0 + 1, x1 = x0 + 1;

            bool y0v = (y0 >= 0) & (y0 < H), y1v = (y1 >= 0) & (y1 < H);
            bool x0v = (x0 >= 0) & (x0 < W), x1v = (x1 >= 0) & (x1 < W);
            int y0c = min(max(y0, 0), H-1), y1c = min(max(y1, 0), H-1);
            int x0c = min(max(x0, 0), W-1), x1c = min(max(x1, 0), W-1);

            DI[wid][k][px] = ((b << 14) + y0c * 128 + x0c)
                           | ((x1c - x0c) << 16) | ((y1c - y0c) << 17);
            f32x4 wv;
            wv[0] = (1.f - ly) * (1.f - lx) * m * ((y0v & x0v) ? 1.f : 0.f);
            wv[1] = (1.f - ly) * lx         * m * ((y0v & x1v) ? 1.f : 0.f);
            wv[2] = ly         * (1.f - lx) * m * ((y1v & x0v) ? 1.f : 0.f);
            wv[3] = ly         * lx         * m * ((y1v & x1v) ? 1.f : 0.f);
            DW[wid][k][px] = wv;
        }
    }

    // ---- register-direct gather + MFMA: 9 k-points x 2 halves, no barriers ----
    const uint4* x4 = (const uint4*)xn;          // row = 8 uint4 (64 bf16 ch)
    const int l15 = lane & 15;
    const int cs  = lane >> 4;                   // channel-slice within half
    const unsigned short* wp = wt2 + l15 * 576 + cs * 8;   // A: row=cout(l15)

    f32x4 acc0 = {}, acc1 = {}, acc2 = {}, acc3 = {};

    int   dcur = DI[wid][0][l15];
    f32x4 wcur = DW[wid][0][l15];

    #pragma unroll 1
    for (int k = 0; k < KK; ++k) {
        int d = dcur;  f32x4 wv = wcur;
        if (k < KK - 1) { dcur = DI[wid][k + 1][l15]; wcur = DW[wid][k + 1][l15]; }

        unsigned p00 = (unsigned)d & 0xFFFFu;
        unsigned o01 = (((unsigned)d >> 16) & 1u) << 3;    // +1 px   (uint4 units)
        unsigned o10 = (((unsigned)d >> 17) & 1u) << 10;   // +1 row
        unsigned b4  = (p00 << 3) + (unsigned)cs;

        #pragma unroll
        for (int half = 0; half < 2; ++half) {
            unsigned base4 = b4 + half * 4;
            uint4 c00 = x4[base4];
            uint4 c01 = x4[base4 + o01];
            uint4 c10 = x4[base4 + o10];
            uint4 c11 = x4[base4 + o01 + o10];

            const int step = 2 * k + half;
            bf16x8 a0 = *(const bf16x8*)(wp + step * 32);
            bf16x8 a1 = *(const bf16x8*)(wp + 16 * 576 + step * 32);
            bf16x8 a2 = *(const bf16x8*)(wp + 32 * 576 + step * 32);
            bf16x8 a3 = *(const bf16x8*)(wp + 48 * 576 + step * 32);

            unsigned pkx = bil_pack(c00.x, c01.x, c10.x, c11.x, wv);
            unsigned pky = bil_pack(c00.y, c01.y, c10.y, c11.y, wv);
            unsigned pkz = bil_pack(c00.z, c01.z, c10.z, c11.z, wv);
            unsigned pkw = bil_pack(c00.w, c01.w, c10.w, c11.w, wv);
            uint4 pk4 = make_uint4(pkx, pky, pkz, pkw);
            bf16x8 bfrag = __builtin_bit_cast(bf16x8, pk4);

            acc0 = __builtin_amdgcn_mfma_f32_16x16x32_bf16(a0, bfrag, acc0, 0, 0, 0);
            acc1 = __builtin_amdgcn_mfma_f32_16x16x32_bf16(a1, bfrag, acc1, 0, 0, 0);
            acc2 = __builtin_amdgcn_mfma_f32_16x16x32_bf16(a2, bfrag, acc2, 0, 0, 0);
            acc3 = __builtin_amdgcn_mfma_f32_16x16x32_bf16(a3, bfrag, acc3, 0, 0, 0);
        }
    }

    // ---- epilogue: D col = px (l15), rows = couts (lane>>4)*4+q, og*16 ----
    const int ox = px0 + l15;
    const int r0 = (lane >> 4) * 4;
    #pragma unroll
    for (int og = 0; og < 4; ++og) {
        f32x4 a = (og == 0) ? acc0 : (og == 1) ? acc1 : (og == 2) ? acc2 : acc3;
        f32x4 bv = *(const f32x4*)(bias + og * 16 + r0);
        #pragma unroll
        for (int q = 0; q < 4; ++q) {
            int o = og * 16 + r0 + q;
            out[(((size_t)(b * 64 + o)) * 128 + oy) * 128 + ox] = a[q] + bv[q];
        }
    }
}

extern "C" void kernel_launch(void* const* d_in, const int* in_sizes, int n_in,
                              void* d_out, int out_size, void* d_ws, size_t ws_size,
                              hipStream_t stream) {
    const float* x    = (const float*)d_in[0];
    const float* offs = (const float*)d_in[1];
    const float* mask = (const float*)d_in[2];
    const float* w    = (const float*)d_in[3];
    const float* bias = (const float*)d_in[4];
    float* out = (float*)d_out;

    char* ws = (char*)d_ws;
    unsigned short* xn  = (unsigned short*)(ws);               // 8 MB bf16 NHWC
    unsigned short* wt2 = (unsigned short*)(ws + (8u << 20));  // 72 KB

    hipLaunchKernelGGL(prep, dim3(1168), dim3(256), 0, stream, x, w, xn, wt2);
    hipLaunchKernelGGL(dcn_main, dim3(1024), dim3(256), 0, stream,
                       xn, wt2, offs, mask, bias, out);
}

// Round 10
// 80.377 us; speedup vs baseline: 1.0156x; 1.0156x over previous
//
#include <hip/hip_runtime.h>

#define BATCH 4
#define CIN 64
#define H 128
#define W 128
#define COUT 64
#define KK 9
#define HO 128
#define WO 128

typedef short bf16x8 __attribute__((ext_vector_type(8)));
typedef float f32x4 __attribute__((ext_vector_type(4)));

__device__ __forceinline__ unsigned short f2bf(float f) {
    unsigned u = __builtin_bit_cast(unsigned, f);
    u += 0x7FFFu + ((u >> 16) & 1u);          // RNE
    return (unsigned short)(u >> 16);
}
__device__ __forceinline__ float bflo(unsigned u) {   // low bf16 of dword
    return __builtin_bit_cast(float, u << 16);
}
__device__ __forceinline__ float bfhi(unsigned u) {   // high bf16 of dword
    return __builtin_bit_cast(float, u & 0xFFFF0000u);
}

// bilinear on one packed dword-column (2 channels), pack result to bf16x2
__device__ __forceinline__ unsigned bil_pack(unsigned u0, unsigned u1,
                                             unsigned u2, unsigned u3, f32x4 wv) {
    float lo = fmaf(wv[0], bflo(u0), fmaf(wv[1], bflo(u1),
               fmaf(wv[2], bflo(u2), wv[3] * bflo(u3))));
    float hi = fmaf(wv[0], bfhi(u0), fmaf(wv[1], bfhi(u1),
               fmaf(wv[2], bfhi(u2), wv[3] * bfhi(u3))));
    unsigned pk;
    asm("v_cvt_pk_bf16_f32 %0, %1, %2" : "=v"(pk) : "v"(lo), "v"(hi));
    return pk;
}

// Prep: blocks 0..1023 NCHW->NHWC bf16 transpose; 1024..1167 weight transpose
__global__ __launch_bounds__(256)
void prep(const float* __restrict__ x, const float* __restrict__ w,
          unsigned short* __restrict__ xn, unsigned short* __restrict__ wt2) {
    const int blk = blockIdx.x;
    const int tid = threadIdx.x;

    if (blk >= 1024) {
        int g = (blk - 1024) * 256 + tid;     // 0..36863
        int o = g / 576;
        int rem = g - o * 576;
        int k = rem >> 6, c = rem & 63;
        wt2[g] = f2bf(w[(o * 64 + c) * 9 + k]);
        return;
    }

    const int b = blk >> 8, oy = (blk >> 1) & 127, xh = blk & 1;

    __shared__ float T[64][65];
    const int px = tid & 63, cq = tid >> 6;
    const float* src = x + (((size_t)b * 64) << 14) + oy * 128 + xh * 64;
    #pragma unroll
    for (int j = 0; j < 16; ++j) {
        int c = cq * 16 + j;
        T[c][px] = src[((size_t)c << 14) + px];
    }
    __syncthreads();
    const int c2 = tid & 63, pq = tid >> 6;
    unsigned short* dst = xn + ((((size_t)b << 14) + oy * 128 + xh * 64) << 6) + c2;
    #pragma unroll
    for (int j = 0; j < 16; ++j) {
        int p = pq * 16 + j;
        dst[(size_t)p << 6] = f2bf(T[c2][p]);
    }
}

__global__ __launch_bounds__(256, 2)
void dcn_main(const unsigned short* __restrict__ xn, const unsigned short* __restrict__ wt2,
              const float* __restrict__ offs, const float* __restrict__ mask,
              const float* __restrict__ bias, float* __restrict__ out) {
    const int tid  = threadIdx.x;
    const int lane = tid & 63;
    const int wid  = tid >> 6;
    const int blk  = blockIdx.x;            // 0..1023 = b*256 + oy*2 + xh
    const int b    = blk >> 8;
    const int oy   = (blk >> 1) & 127;
    const int xh   = blk & 1;
    const int px0  = xh * 64 + wid * 16;    // this wave's 16-px tile

    __shared__ int   DI[4][KK][16];
    __shared__ __align__(16) f32x4 DW[4][KK][16];

    // ---- per-wave descriptor compute: 144 descs over 64 lanes (no barrier) ----
    #pragma unroll
    for (int r = 0; r < 3; ++r) {
        int s = r * 64 + lane;
        if (s < 144) {
            int k = s >> 4, px = s & 15;
            int ox = px0 + px;
            int kh = k / 3, kw = k - kh * 3;

            float offy = offs[((b * 18 + 2 * k    ) * 128 + oy) * 128 + ox];
            float offx = offs[((b * 18 + 2 * k + 1) * 128 + oy) * 128 + ox];
            float m    = mask[((b * 9  + k        ) * 128 + oy) * 128 + ox];

            float py  = (float)(oy - 1 + kh) + offy;
            float pxf = (float)(ox - 1 + kw) + offx;
            float fy = floorf(py), fx = floorf(pxf);
            float ly = py - fy, lx = pxf - fx;
            int y0 = (int)fy, x0 = (int)fx;
            int y1 = y0 + 1, x1 = x0 + 1;

            bool y0v = (y0 >= 0) & (y0 < H), y1v = (y1 >= 0) & (y1 < H);
            bool x0v = (x0 >= 0) & (x0 < W), x1v = (x1 >= 0) & (x1 < W);
            int y0c = min(max(y0, 0), H-1), y1c = min(max(y1, 0), H-1);
            int x0c = min(max(x0, 0), W-1), x1c = min(max(x1, 0), W-1);

            DI[wid][k][px] = ((b << 14) + y0c * 128 + x0c)
                           | ((x1c - x0c) << 16) | ((y1c - y0c) << 17);
            f32x4 wv;
            wv[0] = (1.f - ly) * (1.f - lx) * m * ((y0v & x0v) ? 1.f : 0.f);
            wv[1] = (1.f - ly) * lx         * m * ((y0v & x1v) ? 1.f : 0.f);
            wv[2] = ly         * (1.f - lx) * m * ((y1v & x0v) ? 1.f : 0.f);
            wv[3] = ly         * lx         * m * ((y1v & x1v) ? 1.f : 0.f);
            DW[wid][k][px] = wv;
        }
    }

    // ---- register-direct gather + MFMA, explicit A/B k-stage pipeline ----
    const uint4* x4 = (const uint4*)xn;          // row = 8 uint4 (64 bf16 ch)
    const int l15 = lane & 15;
    const int cs  = lane >> 4;                   // channel-slice within half
    const unsigned short* wp = wt2 + l15 * 576 + cs * 8;   // A: row=cout(l15)

    f32x4 acc0 = {}, acc1 = {}, acc2 = {}, acc3 = {};

    // stage buffers: 8 corners (uint4) + 8 A-frags (bf16x8) + wv, all named
    #define DECLBUF(S) \
        uint4 S##c0, S##c1, S##c2, S##c3, S##c4, S##c5, S##c6, S##c7; \
        bf16x8 S##a0, S##a1, S##a2, S##a3, S##a4, S##a5, S##a6, S##a7; \
        f32x4 S##wv;

    #define LOADK(K, S) { \
        unsigned d_ = (unsigned)DI[wid][(K)][l15]; \
        S##wv = DW[wid][(K)][l15]; \
        unsigned o01_ = ((d_ >> 16) & 1u) << 3; \
        unsigned o10_ = ((d_ >> 17) & 1u) << 10; \
        unsigned b4_  = ((d_ & 0xFFFFu) << 3) + (unsigned)cs; \
        S##c0 = x4[b4_];               S##c1 = x4[b4_ + o01_]; \
        S##c2 = x4[b4_ + o10_];        S##c3 = x4[b4_ + o01_ + o10_]; \
        S##c4 = x4[b4_ + 4];           S##c5 = x4[b4_ + 4 + o01_]; \
        S##c6 = x4[b4_ + 4 + o10_];    S##c7 = x4[b4_ + 4 + o01_ + o10_]; \
        S##a0 = *(const bf16x8*)(wp +            (2*(K)    ) * 32); \
        S##a1 = *(const bf16x8*)(wp + 16 * 576 + (2*(K)    ) * 32); \
        S##a2 = *(const bf16x8*)(wp + 32 * 576 + (2*(K)    ) * 32); \
        S##a3 = *(const bf16x8*)(wp + 48 * 576 + (2*(K)    ) * 32); \
        S##a4 = *(const bf16x8*)(wp +            (2*(K) + 1) * 32); \
        S##a5 = *(const bf16x8*)(wp + 16 * 576 + (2*(K) + 1) * 32); \
        S##a6 = *(const bf16x8*)(wp + 32 * 576 + (2*(K) + 1) * 32); \
        S##a7 = *(const bf16x8*)(wp + 48 * 576 + (2*(K) + 1) * 32); }

    #define COMPK(S) { \
        uint4 pk0_; \
        pk0_.x = bil_pack(S##c0.x, S##c1.x, S##c2.x, S##c3.x, S##wv); \
        pk0_.y = bil_pack(S##c0.y, S##c1.y, S##c2.y, S##c3.y, S##wv); \
        pk0_.z = bil_pack(S##c0.z, S##c1.z, S##c2.z, S##c3.z, S##wv); \
        pk0_.w = bil_pack(S##c0.w, S##c1.w, S##c2.w, S##c3.w, S##wv); \
        bf16x8 bf0_ = __builtin_bit_cast(bf16x8, pk0_); \
        acc0 = __builtin_amdgcn_mfma_f32_16x16x32_bf16(S##a0, bf0_, acc0, 0, 0, 0); \
        acc1 = __builtin_amdgcn_mfma_f32_16x16x32_bf16(S##a1, bf0_, acc1, 0, 0, 0); \
        acc2 = __builtin_amdgcn_mfma_f32_16x16x32_bf16(S##a2, bf0_, acc2, 0, 0, 0); \
        acc3 = __builtin_amdgcn_mfma_f32_16x16x32_bf16(S##a3, bf0_, acc3, 0, 0, 0); \
        uint4 pk1_; \
        pk1_.x = bil_pack(S##c4.x, S##c5.x, S##c6.x, S##c7.x, S##wv); \
        pk1_.y = bil_pack(S##c4.y, S##c5.y, S##c6.y, S##c7.y, S##wv); \
        pk1_.z = bil_pack(S##c4.z, S##c5.z, S##c6.z, S##c7.z, S##wv); \
        pk1_.w = bil_pack(S##c4.w, S##c5.w, S##c6.w, S##c7.w, S##wv); \
        bf16x8 bf1_ = __builtin_bit_cast(bf16x8, pk1_); \
        acc0 = __builtin_amdgcn_mfma_f32_16x16x32_bf16(S##a4, bf1_, acc0, 0, 0, 0); \
        acc1 = __builtin_amdgcn_mfma_f32_16x16x32_bf16(S##a5, bf1_, acc1, 0, 0, 0); \
        acc2 = __builtin_amdgcn_mfma_f32_16x16x32_bf16(S##a6, bf1_, acc2, 0, 0, 0); \
        acc3 = __builtin_amdgcn_mfma_f32_16x16x32_bf16(S##a7, bf1_, acc3, 0, 0, 0); }

    DECLBUF(A) DECLBUF(B)
    LOADK(0, A)
    LOADK(1, B)
    COMPK(A)  LOADK(2, A)
    COMPK(B)  LOADK(3, B)
    COMPK(A)  LOADK(4, A)
    COMPK(B)  LOADK(5, B)
    COMPK(A)  LOADK(6, A)
    COMPK(B)  LOADK(7, B)
    COMPK(A)  LOADK(8, A)
    COMPK(B)
    COMPK(A)

    #undef DECLBUF
    #undef LOADK
    #undef COMPK

    // ---- epilogue: D col = px (l15), rows = couts (lane>>4)*4+q, og*16 ----
    const int ox = px0 + l15;
    const int r0 = (lane >> 4) * 4;
    #pragma unroll
    for (int og = 0; og < 4; ++og) {
        f32x4 a = (og == 0) ? acc0 : (og == 1) ? acc1 : (og == 2) ? acc2 : acc3;
        f32x4 bv = *(const f32x4*)(bias + og * 16 + r0);
        #pragma unroll
        for (int q = 0; q < 4; ++q) {
            int o = og * 16 + r0 + q;
            out[(((size_t)(b * 64 + o)) * 128 + oy) * 128 + ox] = a[q] + bv[q];
        }
    }
}

extern "C" void kernel_launch(void* const* d_in, const int* in_sizes, int n_in,
                              void* d_out, int out_size, void* d_ws, size_t ws_size,
                              hipStream_t stream) {
    const float* x    = (const float*)d_in[0];
    const float* offs = (const float*)d_in[1];
    const float* mask = (const float*)d_in[2];
    const float* w    = (const float*)d_in[3];
    const float* bias = (const float*)d_in[4];
    float* out = (float*)d_out;

    char* ws = (char*)d_ws;
    unsigned short* xn  = (unsigned short*)(ws);               // 8 MB bf16 NHWC
    unsigned short* wt2 = (unsigned short*)(ws + (8u << 20));  // 72 KB

    hipLaunchKernelGGL(prep, dim3(1168), dim3(256), 0, stream, x, w, xn, wt2);
    hipLaunchKernelGGL(dcn_main, dim3(1024), dim3(256), 0, stream,
                       xn, wt2, offs, mask, bias, out);
}

// Round 11
// 79.583 us; speedup vs baseline: 1.0258x; 1.0100x over previous
//
#include <hip/hip_runtime.h>

#define BATCH 4
#define CIN 64
#define H 128
#define W 128
#define COUT 64
#define KK 9
#define HO 128
#define WO 128

typedef short bf16x8 __attribute__((ext_vector_type(8)));
typedef float f32x4 __attribute__((ext_vector_type(4)));

__device__ __forceinline__ unsigned short f2bf(float f) {
    unsigned u = __builtin_bit_cast(unsigned, f);
    u += 0x7FFFu + ((u >> 16) & 1u);          // RNE
    return (unsigned short)(u >> 16);
}
__device__ __forceinline__ float bflo(unsigned u) {   // low bf16 of dword
    return __builtin_bit_cast(float, u << 16);
}
__device__ __forceinline__ float bfhi(unsigned u) {   // high bf16 of dword
    return __builtin_bit_cast(float, u & 0xFFFF0000u);
}

// bilinear on one packed dword-column (2 channels), pack result to bf16x2
__device__ __forceinline__ unsigned bil_pack(unsigned u0, unsigned u1,
                                             unsigned u2, unsigned u3, f32x4 wv) {
    float lo = fmaf(wv[0], bflo(u0), fmaf(wv[1], bflo(u1),
               fmaf(wv[2], bflo(u2), wv[3] * bflo(u3))));
    float hi = fmaf(wv[0], bfhi(u0), fmaf(wv[1], bfhi(u1),
               fmaf(wv[2], bfhi(u2), wv[3] * bfhi(u3))));
    unsigned pk;
    asm("v_cvt_pk_bf16_f32 %0, %1, %2" : "=v"(pk) : "v"(lo), "v"(hi));
    return pk;
}

// Prep: blocks 0..1023 NCHW->NHWC bf16 transpose; 1024..1167 weight transpose
__global__ __launch_bounds__(256)
void prep(const float* __restrict__ x, const float* __restrict__ w,
          unsigned short* __restrict__ xn, unsigned short* __restrict__ wt2) {
    const int blk = blockIdx.x;
    const int tid = threadIdx.x;

    if (blk >= 1024) {
        int g = (blk - 1024) * 256 + tid;     // 0..36863
        int o = g / 576;
        int rem = g - o * 576;
        int k = rem >> 6, c = rem & 63;
        wt2[g] = f2bf(w[(o * 64 + c) * 9 + k]);
        return;
    }

    const int b = blk >> 8, oy = (blk >> 1) & 127, xh = blk & 1;

    __shared__ float T[64][65];
    const int px = tid & 63, cq = tid >> 6;
    const float* src = x + (((size_t)b * 64) << 14) + oy * 128 + xh * 64;
    #pragma unroll
    for (int j = 0; j < 16; ++j) {
        int c = cq * 16 + j;
        T[c][px] = src[((size_t)c << 14) + px];
    }
    __syncthreads();
    const int c2 = tid & 63, pq = tid >> 6;
    unsigned short* dst = xn + ((((size_t)b << 14) + oy * 128 + xh * 64) << 6) + c2;
    #pragma unroll
    for (int j = 0; j < 16; ++j) {
        int p = pq * 16 + j;
        dst[(size_t)p << 6] = f2bf(T[c2][p]);
    }
}

__global__ __launch_bounds__(256, 3)
void dcn_main(const unsigned short* __restrict__ xn, const unsigned short* __restrict__ wt2,
              const float* __restrict__ offs, const float* __restrict__ mask,
              const float* __restrict__ bias, float* __restrict__ out) {
    const int tid  = threadIdx.x;
    const int lane = tid & 63;
    const int wid  = tid >> 6;
    const int blk  = blockIdx.x;            // 0..1023 = b*256 + oy*2 + xh
    const int b    = blk >> 8;
    const int oy   = (blk >> 1) & 127;
    const int xh   = blk & 1;
    const int px0  = xh * 64 + wid * 16;    // this wave's 16-px tile

    __shared__ int   DI[4][KK][16];
    __shared__ __align__(16) f32x4 DW[4][KK][16];

    // ---- per-wave descriptor compute: 144 descs over 64 lanes (no barrier) ----
    #pragma unroll
    for (int r = 0; r < 3; ++r) {
        int s = r * 64 + lane;
        if (s < 144) {
            int k = s >> 4, px = s & 15;
            int ox = px0 + px;
            int kh = k / 3, kw = k - kh * 3;

            float offy = offs[((b * 18 + 2 * k    ) * 128 + oy) * 128 + ox];
            float offx = offs[((b * 18 + 2 * k + 1) * 128 + oy) * 128 + ox];
            float m    = mask[((b * 9  + k        ) * 128 + oy) * 128 + ox];

            float py  = (float)(oy - 1 + kh) + offy;
            float pxf = (float)(ox - 1 + kw) + offx;
            float fy = floorf(py), fx = floorf(pxf);
            float ly = py - fy, lx = pxf - fx;
            int y0 = (int)fy, x0 = (int)fx;
            int y1 = y0 + 1, x1 = x0 + 1;

            bool y0v = (y0 >= 0) & (y0 < H), y1v = (y1 >= 0) & (y1 < H);
            bool x0v = (x0 >= 0) & (x0 < W), x1v = (x1 >= 0) & (x1 < W);
            int y0c = min(max(y0, 0), H-1), y1c = min(max(y1, 0), H-1);
            int x0c = min(max(x0, 0), W-1), x1c = min(max(x1, 0), W-1);

            DI[wid][k][px] = ((b << 14) + y0c * 128 + x0c)
                           | ((x1c - x0c) << 16) | ((y1c - y0c) << 17);
            f32x4 wv;
            wv[0] = (1.f - ly) * (1.f - lx) * m * ((y0v & x0v) ? 1.f : 0.f);
            wv[1] = (1.f - ly) * lx         * m * ((y0v & x1v) ? 1.f : 0.f);
            wv[2] = ly         * (1.f - lx) * m * ((y1v & x0v) ? 1.f : 0.f);
            wv[3] = ly         * lx         * m * ((y1v & x1v) ? 1.f : 0.f);
            DW[wid][k][px] = wv;
        }
    }

    // ---- register-direct gather + MFMA, sched_barrier-pinned pipeline ----
    const uint4* x4 = (const uint4*)xn;          // row = 8 uint4 (64 bf16 ch)
    const int l15 = lane & 15;
    const int cs  = lane >> 4;                   // channel-slice
    const unsigned short* wp = wt2 + l15 * 576 + cs * 8;   // A: row=cout(l15)

    f32x4 acc0 = {}, acc1 = {}, acc2 = {}, acc3 = {};

    #define SB __builtin_amdgcn_sched_barrier(0)

    // half-k stage: 4 corner uint4 + 4 A-frags + weight vec  (~36 VGPR/set)
    #define DECLS(S) \
        uint4 S##c0, S##c1, S##c2, S##c3; \
        bf16x8 S##a0, S##a1, S##a2, S##a3; \
        f32x4 S##wv;

    #define HLOAD(HS, S) { \
        const int k_ = (HS) >> 1, hf_ = (HS) & 1; \
        unsigned d_ = (unsigned)DI[wid][k_][l15]; \
        S##wv = DW[wid][k_][l15]; \
        unsigned o01_ = ((d_ >> 16) & 1u) << 3; \
        unsigned o10_ = ((d_ >> 17) & 1u) << 10; \
        unsigned b4_  = ((d_ & 0xFFFFu) << 3) + (unsigned)cs + (hf_ ? 4u : 0u); \
        S##c0 = x4[b4_];          S##c1 = x4[b4_ + o01_]; \
        S##c2 = x4[b4_ + o10_];   S##c3 = x4[b4_ + o01_ + o10_]; \
        S##a0 = *(const bf16x8*)(wp +            (HS) * 32); \
        S##a1 = *(const bf16x8*)(wp + 16 * 576 + (HS) * 32); \
        S##a2 = *(const bf16x8*)(wp + 32 * 576 + (HS) * 32); \
        S##a3 = *(const bf16x8*)(wp + 48 * 576 + (HS) * 32); }

    #define HCOMP(S) { \
        uint4 pk_; \
        pk_.x = bil_pack(S##c0.x, S##c1.x, S##c2.x, S##c3.x, S##wv); \
        pk_.y = bil_pack(S##c0.y, S##c1.y, S##c2.y, S##c3.y, S##wv); \
        pk_.z = bil_pack(S##c0.z, S##c1.z, S##c2.z, S##c3.z, S##wv); \
        pk_.w = bil_pack(S##c0.w, S##c1.w, S##c2.w, S##c3.w, S##wv); \
        bf16x8 bf_ = __builtin_bit_cast(bf16x8, pk_); \
        acc0 = __builtin_amdgcn_mfma_f32_16x16x32_bf16(S##a0, bf_, acc0, 0, 0, 0); \
        acc1 = __builtin_amdgcn_mfma_f32_16x16x32_bf16(S##a1, bf_, acc1, 0, 0, 0); \
        acc2 = __builtin_amdgcn_mfma_f32_16x16x32_bf16(S##a2, bf_, acc2, 0, 0, 0); \
        acc3 = __builtin_amdgcn_mfma_f32_16x16x32_bf16(S##a3, bf_, acc3, 0, 0, 0); }

    DECLS(A) DECLS(B)
    HLOAD(0, A)
    SB;
    HLOAD(1, B)
    SB;
    HCOMP(A) HLOAD(2, A)   SB;   // region: compute hs, refill same buffer w/ hs+2
    HCOMP(B) HLOAD(3, B)   SB;
    HCOMP(A) HLOAD(4, A)   SB;
    HCOMP(B) HLOAD(5, B)   SB;
    HCOMP(A) HLOAD(6, A)   SB;
    HCOMP(B) HLOAD(7, B)   SB;
    HCOMP(A) HLOAD(8, A)   SB;
    HCOMP(B) HLOAD(9, B)   SB;
    HCOMP(A) HLOAD(10, A)  SB;
    HCOMP(B) HLOAD(11, B)  SB;
    HCOMP(A) HLOAD(12, A)  SB;
    HCOMP(B) HLOAD(13, B)  SB;
    HCOMP(A) HLOAD(14, A)  SB;
    HCOMP(B) HLOAD(15, B)  SB;
    HCOMP(A) HLOAD(16, A)  SB;
    HCOMP(B) HLOAD(17, B)  SB;
    HCOMP(A)
    SB;
    HCOMP(B)

    #undef DECLS
    #undef HLOAD
    #undef HCOMP
    #undef SB

    // ---- epilogue: D col = px (l15), rows = couts (lane>>4)*4+q, og*16 ----
    const int ox = px0 + l15;
    const int r0 = (lane >> 4) * 4;
    #pragma unroll
    for (int og = 0; og < 4; ++og) {
        f32x4 a = (og == 0) ? acc0 : (og == 1) ? acc1 : (og == 2) ? acc2 : acc3;
        f32x4 bv = *(const f32x4*)(bias + og * 16 + r0);
        #pragma unroll
        for (int q = 0; q < 4; ++q) {
            int o = og * 16 + r0 + q;
            out[(((size_t)(b * 64 + o)) * 128 + oy) * 128 + ox] = a[q] + bv[q];
        }
    }
}

extern "C" void kernel_launch(void* const* d_in, const int* in_sizes, int n_in,
                              void* d_out, int out_size, void* d_ws, size_t ws_size,
                              hipStream_t stream) {
    const float* x    = (const float*)d_in[0];
    const float* offs = (const float*)d_in[1];
    const float* mask = (const float*)d_in[2];
    const float* w    = (const float*)d_in[3];
    const float* bias = (const float*)d_in[4];
    float* out = (float*)d_out;

    char* ws = (char*)d_ws;
    unsigned short* xn  = (unsigned short*)(ws);               // 8 MB bf16 NHWC
    unsigned short* wt2 = (unsigned short*)(ws + (8u << 20));  // 72 KB

    hipLaunchKernelGGL(prep, dim3(1168), dim3(256), 0, stream, x, w, xn, wt2);
    hipLaunchKernelGGL(dcn_main, dim3(1024), dim3(256), 0, stream,
                       xn, wt2, offs, mask, bias, out);
}

// Round 12
// 79.166 us; speedup vs baseline: 1.0312x; 1.0053x over previous
//
#include <hip/hip_runtime.h>

#define BATCH 4
#define CIN 64
#define H 128
#define W 128
#define COUT 64
#define KK 9
#define HO 128
#define WO 128

typedef short bf16x8 __attribute__((ext_vector_type(8)));
typedef float f32x4 __attribute__((ext_vector_type(4)));
typedef unsigned u32x4 __attribute__((ext_vector_type(4)));

__device__ __forceinline__ unsigned short f2bf(float f) {
    unsigned u = __builtin_bit_cast(unsigned, f);
    u += 0x7FFFu + ((u >> 16) & 1u);          // RNE
    return (unsigned short)(u >> 16);
}
__device__ __forceinline__ float bflo(unsigned u) {   // low bf16 of dword
    return __builtin_bit_cast(float, u << 16);
}
__device__ __forceinline__ float bfhi(unsigned u) {   // high bf16 of dword
    return __builtin_bit_cast(float, u & 0xFFFF0000u);
}

// bilinear on one packed dword-column (2 channels), pack result to bf16x2
__device__ __forceinline__ unsigned bil_pack(unsigned u0, unsigned u1,
                                             unsigned u2, unsigned u3, f32x4 wv) {
    float lo = fmaf(wv[0], bflo(u0), fmaf(wv[1], bflo(u1),
               fmaf(wv[2], bflo(u2), wv[3] * bflo(u3))));
    float hi = fmaf(wv[0], bfhi(u0), fmaf(wv[1], bfhi(u1),
               fmaf(wv[2], bfhi(u2), wv[3] * bfhi(u3))));
    unsigned pk;
    asm("v_cvt_pk_bf16_f32 %0, %1, %2" : "=v"(pk) : "v"(lo), "v"(hi));
    return pk;
}

// Prep: blocks 0..1023 NCHW->NHWC bf16 transpose; 1024..1167 weight transpose
__global__ __launch_bounds__(256)
void prep(const float* __restrict__ x, const float* __restrict__ w,
          unsigned short* __restrict__ xn, unsigned short* __restrict__ wt2) {
    const int blk = blockIdx.x;
    const int tid = threadIdx.x;

    if (blk >= 1024) {
        int g = (blk - 1024) * 256 + tid;     // 0..36863
        int o = g / 576;
        int rem = g - o * 576;
        int k = rem >> 6, c = rem & 63;
        wt2[g] = f2bf(w[(o * 64 + c) * 9 + k]);
        return;
    }

    const int b = blk >> 8, oy = (blk >> 1) & 127, xh = blk & 1;

    __shared__ float T[64][65];
    const int px = tid & 63, cq = tid >> 6;
    const float* src = x + (((size_t)b * 64) << 14) + oy * 128 + xh * 64;
    #pragma unroll
    for (int j = 0; j < 16; ++j) {
        int c = cq * 16 + j;
        T[c][px] = src[((size_t)c << 14) + px];
    }
    __syncthreads();
    const int c2 = tid & 63, pq = tid >> 6;
    unsigned short* dst = xn + ((((size_t)b << 14) + oy * 128 + xh * 64) << 6) + c2;
    #pragma unroll
    for (int j = 0; j < 16; ++j) {
        int p = pq * 16 + j;
        dst[(size_t)p << 6] = f2bf(T[c2][p]);
    }
}

__global__ __launch_bounds__(256, 3)
void dcn_main(const unsigned short* __restrict__ xn, const unsigned short* __restrict__ wt2,
              const float* __restrict__ offs, const float* __restrict__ mask,
              const float* __restrict__ bias, float* __restrict__ out) {
    const int tid  = threadIdx.x;
    const int lane = tid & 63;
    const int wid  = tid >> 6;
    const int blk  = blockIdx.x;            // 0..1023 = b*256 + oy*2 + xh
    const int b    = blk >> 8;
    const int oy   = (blk >> 1) & 127;
    const int xh   = blk & 1;
    const int px0  = xh * 64 + wid * 16;    // this wave's 16-px tile

    __shared__ int   DI[4][KK][16];
    __shared__ __align__(16) f32x4 DW[4][KK][16];

    // ---- per-wave descriptor compute: 144 descs over 64 lanes (no barrier) ----
    #pragma unroll
    for (int r = 0; r < 3; ++r) {
        int s = r * 64 + lane;
        if (s < 144) {
            int k = s >> 4, px = s & 15;
            int ox = px0 + px;
            int kh = k / 3, kw = k - kh * 3;

            float offy = offs[((b * 18 + 2 * k    ) * 128 + oy) * 128 + ox];
            float offx = offs[((b * 18 + 2 * k + 1) * 128 + oy) * 128 + ox];
            float m    = mask[((b * 9  + k        ) * 128 + oy) * 128 + ox];

            float py  = (float)(oy - 1 + kh) + offy;
            float pxf = (float)(ox - 1 + kw) + offx;
            float fy = floorf(py), fx = floorf(pxf);
            float ly = py - fy, lx = pxf - fx;
            int y0 = (int)fy, x0 = (int)fx;
            int y1 = y0 + 1, x1 = x0 + 1;

            bool y0v = (y0 >= 0) & (y0 < H), y1v = (y1 >= 0) & (y1 < H);
            bool x0v = (x0 >= 0) & (x0 < W), x1v = (x1 >= 0) & (x1 < W);
            int y0c = min(max(y0, 0), H-1), y1c = min(max(y1, 0), H-1);
            int x0c = min(max(x0, 0), W-1), x1c = min(max(x1, 0), W-1);

            DI[wid][k][px] = ((b << 14) + y0c * 128 + x0c)
                           | ((x1c - x0c) << 16) | ((y1c - y0c) << 17);
            f32x4 wv;
            wv[0] = (1.f - ly) * (1.f - lx) * m * ((y0v & x0v) ? 1.f : 0.f);
            wv[1] = (1.f - ly) * lx         * m * ((y0v & x1v) ? 1.f : 0.f);
            wv[2] = ly         * (1.f - lx) * m * ((y1v & x0v) ? 1.f : 0.f);
            wv[3] = ly         * lx         * m * ((y1v & x1v) ? 1.f : 0.f);
            DW[wid][k][px] = wv;
        }
    }

    // ---- register-direct gather + MFMA, inline-asm counted-vmcnt pipeline ----
    const int l15 = lane & 15;
    const int cs  = lane >> 4;                   // channel-slice
    const unsigned csb = (unsigned)cs * 16u;     // corner byte offset of slice
    const unsigned wb  = ((unsigned)l15 * 576u + (unsigned)cs * 8u) * 2u;  // wt2 byte base
    const void* xnp = (const void*)xn;
    const void* wtp = (const void*)wt2;

    f32x4 acc0 = {}, acc1 = {}, acc2 = {}, acc3 = {};

    // volatile saddr-form loads: compiler cannot sink/serialize these
    #define GL4(DST, VOFF, SBASE) \
        asm volatile("global_load_dwordx4 %0, %1, %2" \
                     : "=v"(DST) : "v"(VOFF), "s"(SBASE) : "memory");

    #define SB  __builtin_amdgcn_sched_barrier(0)
    #define WAIT8 { asm volatile("s_waitcnt vmcnt(8)" ::: "memory"); SB; }
    #define WAIT0 { asm volatile("s_waitcnt vmcnt(0)" ::: "memory"); SB; }

    // half-k stage buffers: 4 corner u32x4 + 4 A-frag bf16x8 + wv
    #define DECLS(S) \
        u32x4 S##c0, S##c1, S##c2, S##c3; \
        bf16x8 S##a0, S##a1, S##a2, S##a3; \
        f32x4 S##wv;

    // issue the 8 loads of half-stage HS into buffer S (order: c0..c3,a0..a3)
    #define HLOAD(HS, S) { \
        unsigned d_ = (unsigned)DI[wid][(HS) >> 1][l15]; \
        S##wv = DW[wid][(HS) >> 1][l15]; \
        unsigned o01_ = ((d_ >> 16) & 1u) << 7;             /* +1 px  (bytes) */ \
        unsigned o10_ = ((d_ >> 17) & 1u) << 14;            /* +1 row (bytes) */ \
        unsigned b0_  = ((d_ & 0xFFFFu) << 7) + csb + (((HS) & 1) ? 64u : 0u); \
        GL4(S##c0, b0_, xnp)                 GL4(S##c1, b0_ + o01_, xnp) \
        GL4(S##c2, b0_ + o10_, xnp)          GL4(S##c3, b0_ + o01_ + o10_, xnp) \
        unsigned w0_ = wb + (unsigned)(HS) * 64u; \
        GL4(S##a0, w0_, wtp)                 GL4(S##a1, w0_ + 18432u, wtp) \
        GL4(S##a2, w0_ + 36864u, wtp)        GL4(S##a3, w0_ + 55296u, wtp) }

    #define HCOMP(S) { \
        u32x4 pk_; \
        pk_[0] = bil_pack(S##c0[0], S##c1[0], S##c2[0], S##c3[0], S##wv); \
        pk_[1] = bil_pack(S##c0[1], S##c1[1], S##c2[1], S##c3[1], S##wv); \
        pk_[2] = bil_pack(S##c0[2], S##c1[2], S##c2[2], S##c3[2], S##wv); \
        pk_[3] = bil_pack(S##c0[3], S##c1[3], S##c2[3], S##c3[3], S##wv); \
        bf16x8 bf_ = __builtin_bit_cast(bf16x8, pk_); \
        acc0 = __builtin_amdgcn_mfma_f32_16x16x32_bf16(S##a0, bf_, acc0, 0, 0, 0); \
        acc1 = __builtin_amdgcn_mfma_f32_16x16x32_bf16(S##a1, bf_, acc1, 0, 0, 0); \
        acc2 = __builtin_amdgcn_mfma_f32_16x16x32_bf16(S##a2, bf_, acc2, 0, 0, 0); \
        acc3 = __builtin_amdgcn_mfma_f32_16x16x32_bf16(S##a3, bf_, acc3, 0, 0, 0); }

    DECLS(A) DECLS(B)
    HLOAD(0, A)
    HLOAD(1, B)
    WAIT8  HCOMP(A)  HLOAD(2, A)           // region n: stage n done, issue n+2
    WAIT8  HCOMP(B)  HLOAD(3, B)
    WAIT8  HCOMP(A)  HLOAD(4, A)
    WAIT8  HCOMP(B)  HLOAD(5, B)
    WAIT8  HCOMP(A)  HLOAD(6, A)
    WAIT8  HCOMP(B)  HLOAD(7, B)
    WAIT8  HCOMP(A)  HLOAD(8, A)
    WAIT8  HCOMP(B)  HLOAD(9, B)
    WAIT8  HCOMP(A)  HLOAD(10, A)
    WAIT8  HCOMP(B)  HLOAD(11, B)
    WAIT8  HCOMP(A)  HLOAD(12, A)
    WAIT8  HCOMP(B)  HLOAD(13, B)
    WAIT8  HCOMP(A)  HLOAD(14, A)
    WAIT8  HCOMP(B)  HLOAD(15, B)
    WAIT8  HCOMP(A)  HLOAD(16, A)
    WAIT8  HCOMP(B)  HLOAD(17, B)
    WAIT8  HCOMP(A)                         // stage 16
    WAIT0  HCOMP(B)                         // stage 17

    #undef DECLS
    #undef HLOAD
    #undef HCOMP
    #undef GL4
    #undef WAIT8
    #undef WAIT0
    #undef SB

    // ---- epilogue: D col = px (l15), rows = couts (lane>>4)*4+q, og*16 ----
    const int ox = px0 + l15;
    const int r0 = (lane >> 4) * 4;
    #pragma unroll
    for (int og = 0; og < 4; ++og) {
        f32x4 a = (og == 0) ? acc0 : (og == 1) ? acc1 : (og == 2) ? acc2 : acc3;
        f32x4 bv = *(const f32x4*)(bias + og * 16 + r0);
        #pragma unroll
        for (int q = 0; q < 4; ++q) {
            int o = og * 16 + r0 + q;
            out[(((size_t)(b * 64 + o)) * 128 + oy) * 128 + ox] = a[q] + bv[q];
        }
    }
}

extern "C" void kernel_launch(void* const* d_in, const int* in_sizes, int n_in,
                              void* d_out, int out_size, void* d_ws, size_t ws_size,
                              hipStream_t stream) {
    const float* x    = (const float*)d_in[0];
    const float* offs = (const float*)d_in[1];
    const float* mask = (const float*)d_in[2];
    const float* w    = (const float*)d_in[3];
    const float* bias = (const float*)d_in[4];
    float* out = (float*)d_out;

    char* ws = (char*)d_ws;
    unsigned short* xn  = (unsigned short*)(ws);               // 8 MB bf16 NHWC
    unsigned short* wt2 = (unsigned short*)(ws + (8u << 20));  // 72 KB

    hipLaunchKernelGGL(prep, dim3(1168), dim3(256), 0, stream, x, w, xn, wt2);
    hipLaunchKernelGGL(dcn_main, dim3(1024), dim3(256), 0, stream,
                       xn, wt2, offs, mask, bias, out);
}

// Round 13
// 56.462 us; speedup vs baseline: 1.4458x; 1.4021x over previous
//
#include <hip/hip_runtime.h>

#define BATCH 4
#define CIN 64
#define H 128
#define W 128
#define COUT 64
#define KK 9
#define HO 128
#define WO 128

typedef short bf16x8 __attribute__((ext_vector_type(8)));
typedef float f32x4 __attribute__((ext_vector_type(4)));

__device__ __forceinline__ unsigned short f2bf(float f) {
    unsigned u = __builtin_bit_cast(unsigned, f);
    u += 0x7FFFu + ((u >> 16) & 1u);          // RNE
    return (unsigned short)(u >> 16);
}
__device__ __forceinline__ float bflo(unsigned u) {   // low bf16 of dword
    return __builtin_bit_cast(float, u << 16);
}
__device__ __forceinline__ float bfhi(unsigned u) {   // high bf16 of dword
    return __builtin_bit_cast(float, u & 0xFFFF0000u);
}

// bilinear on one packed dword-column (2 channels), pack result to bf16x2
__device__ __forceinline__ unsigned bil_pack(unsigned u0, unsigned u1,
                                             unsigned u2, unsigned u3, f32x4 wv) {
    float lo = fmaf(wv[0], bflo(u0), fmaf(wv[1], bflo(u1),
               fmaf(wv[2], bflo(u2), wv[3] * bflo(u3))));
    float hi = fmaf(wv[0], bfhi(u0), fmaf(wv[1], bfhi(u1),
               fmaf(wv[2], bfhi(u2), wv[3] * bfhi(u3))));
    unsigned pk;
    asm("v_cvt_pk_bf16_f32 %0, %1, %2" : "=v"(pk) : "v"(lo), "v"(hi));
    return pk;
}

// Prep: blocks 0..1023 NCHW->NHWC bf16 transpose; 1024..1167 weight transpose
__global__ __launch_bounds__(256)
void prep(const float* __restrict__ x, const float* __restrict__ w,
          unsigned short* __restrict__ xn, unsigned short* __restrict__ wt2) {
    const int blk = blockIdx.x;
    const int tid = threadIdx.x;

    if (blk >= 1024) {
        int g = (blk - 1024) * 256 + tid;     // 0..36863
        int o = g / 576;
        int rem = g - o * 576;
        int k = rem >> 6, c = rem & 63;
        wt2[g] = f2bf(w[(o * 64 + c) * 9 + k]);
        return;
    }

    const int b = blk >> 8, oy = (blk >> 1) & 127, xh = blk & 1;

    __shared__ float T[64][65];
    const int px = tid & 63, cq = tid >> 6;
    const float* src = x + (((size_t)b * 64) << 14) + oy * 128 + xh * 64;
    #pragma unroll
    for (int j = 0; j < 16; ++j) {
        int c = cq * 16 + j;
        T[c][px] = src[((size_t)c << 14) + px];
    }
    __syncthreads();
    const int c2 = tid & 63, pq = tid >> 6;
    unsigned short* dst = xn + ((((size_t)b << 14) + oy * 128 + xh * 64) << 6) + c2;
    #pragma unroll
    for (int j = 0; j < 16; ++j) {
        int p = pq * 16 + j;
        dst[(size_t)p << 6] = f2bf(T[c2][p]);
    }
}

// One block = 16-px tile, full K=576. 4096 blocks.
__global__ __launch_bounds__(256, 6)
void dcn_main(const unsigned short* __restrict__ xn, const unsigned short* __restrict__ wt2,
              const float* __restrict__ offs, const float* __restrict__ mask,
              const float* __restrict__ bias, float* __restrict__ out) {
    const int tid  = threadIdx.x;
    const int lane = tid & 63;
    const int wid  = tid >> 6;
    const int blk  = blockIdx.x;            // b*1024 + oy*8 + xq
    const int b    = blk >> 10;
    const int oy   = (blk >> 3) & 127;
    const int xq   = blk & 7;
    const int px0  = xq * 16;

    __shared__ __align__(16) unsigned short S[16 * 576];   // 18 KB swizzled [pxl][r]
    __shared__ int   DI[KK * 16];
    __shared__ __align__(16) f32x4 DW[KK * 16];

    // ---- descriptor phase: one thread per sample (144), then barrier ----
    if (tid < 144) {
        int s = tid;
        int k = s >> 4, px = s & 15;
        int ox = px0 + px;
        int kh = k / 3, kw = k - kh * 3;

        float offy = offs[((b * 18 + 2 * k    ) * 128 + oy) * 128 + ox];
        float offx = offs[((b * 18 + 2 * k + 1) * 128 + oy) * 128 + ox];
        float m    = mask[((b * 9  + k        ) * 128 + oy) * 128 + ox];

        float py  = (float)(oy - 1 + kh) + offy;
        float pxf = (float)(ox - 1 + kw) + offx;
        float fy = floorf(py), fx = floorf(pxf);
        float ly = py - fy, lx = pxf - fx;
        int y0 = (int)fy, x0 = (int)fx;
        int y1 = y0 + 1, x1 = x0 + 1;

        bool y0v = (y0 >= 0) & (y0 < H), y1v = (y1 >= 0) & (y1 < H);
        bool x0v = (x0 >= 0) & (x0 < W), x1v = (x1 >= 0) & (x1 < W);
        int y0c = min(max(y0, 0), H-1), y1c = min(max(y1, 0), H-1);
        int x0c = min(max(x0, 0), W-1), x1c = min(max(x1, 0), W-1);

        DI[s] = ((b << 14) + y0c * 128 + x0c)
              | ((x1c - x0c) << 16) | ((y1c - y0c) << 17);
        f32x4 wv;
        wv[0] = (1.f - ly) * (1.f - lx) * m * ((y0v & x0v) ? 1.f : 0.f);
        wv[1] = (1.f - ly) * lx         * m * ((y0v & x1v) ? 1.f : 0.f);
        wv[2] = ly         * (1.f - lx) * m * ((y1v & x0v) ? 1.f : 0.f);
        wv[3] = ly         * lx         * m * ((y1v & x1v) ? 1.f : 0.f);
        DW[s] = wv;
    }
    __syncthreads();

    // ---- gather: 18 groups of 8 samples, 8 lanes/sample, uint4 corners ----
    const int lg = lane >> 3;               // sample-in-group
    const int lc = lane & 7;                // channel slice (8 ch)
    const uint4* x4 = (const uint4*)xn;

    // group G: k = G>>1, pixel-half = G&1; sample = k*16 + h*8 + lg
    #define GG(G)                                                              \
    {   const int k_ = (G) >> 1, h_ = (G) & 1;                                 \
        const int s_ = k_ * 16 + h_ * 8 + lg;                                  \
        int d = DI[s_];                                                        \
        f32x4 wv = DW[s_];                                                     \
        unsigned p00   = (unsigned)d & 0xFFFFu;                                \
        unsigned base4 = (p00 << 3) + (unsigned)lc;                            \
        unsigned o01   = (((unsigned)d >> 16) & 1u) << 3;                      \
        unsigned o10   = (((unsigned)d >> 17) & 1u) << 10;                     \
        uint4 c00 = x4[base4];                                                 \
        uint4 c01 = x4[base4 + o01];                                           \
        uint4 c10 = x4[base4 + o10];                                           \
        uint4 c11 = x4[base4 + o01 + o10];                                     \
        uint4 pk;                                                              \
        pk.x = bil_pack(c00.x, c01.x, c10.x, c11.x, wv);                       \
        pk.y = bil_pack(c00.y, c01.y, c10.y, c11.y, wv);                       \
        pk.z = bil_pack(c00.z, c01.z, c10.z, c11.z, wv);                       \
        pk.w = bil_pack(c00.w, c01.w, c10.w, c11.w, wv);                       \
        int pxl = h_ * 8 + lg;                                                 \
        int sb = pxl * 1152 + k_ * 128 + ((lc * 16) ^ ((pxl & 7) << 4));       \
        *(uint4*)((char*)S + sb) = pk;                                         \
    }

    if      (wid == 0) { GG(0) GG(4) GG(8)  GG(12) GG(16) }
    else if (wid == 1) { GG(1) GG(5) GG(9)  GG(13) GG(17) }
    else if (wid == 2) { GG(2) GG(6) GG(10) GG(14) }
    else               { GG(3) GG(7) GG(11) GG(15) }
    #undef GG
    __syncthreads();

    // ---- MFMA sweep: 16px x (wave's 16 couts), K=576, afrag depth-1 ----
    f32x4 acc = {};
    {
        const int l15 = lane & 15;
        const int cs  = lane >> 4;
        const unsigned short* wp = wt2 + (wid * 16 + l15) * 576 + cs * 8;
        const int swz  = (l15 & 7) << 4;
        const int bo   = l15 * 1152;
        const int rb   = cs * 16;

        bf16x8 afA = *(const bf16x8*)(wp);
        bf16x8 afB;
        #pragma unroll 1
        for (int ss = 0; ss < 9; ++ss) {
            afB = *(const bf16x8*)(wp + (2 * ss + 1) * 32);
            {
                int colx = (2 * ss * 64 + rb) ^ swz;
                bf16x8 bf = *(const bf16x8*)((const char*)S + bo + colx);
                acc = __builtin_amdgcn_mfma_f32_16x16x32_bf16(afA, bf, acc, 0, 0, 0);
            }
            if (ss < 8) afA = *(const bf16x8*)(wp + (2 * ss + 2) * 32);
            {
                int colx = ((2 * ss + 1) * 64 + rb) ^ swz;
                bf16x8 bf = *(const bf16x8*)((const char*)S + bo + colx);
                acc = __builtin_amdgcn_mfma_f32_16x16x32_bf16(afB, bf, acc, 0, 0, 0);
            }
        }
    }

    // ---- epilogue: col = px (lane&15), row = cout (lane>>4)*4+q ----
    const int ox = px0 + (lane & 15);
    const int r0 = (lane >> 4) * 4;
    #pragma unroll
    for (int q = 0; q < 4; ++q) {
        int o = wid * 16 + r0 + q;
        out[(((size_t)(b * 64 + o)) * 128 + oy) * 128 + ox] = acc[q] + bias[o];
    }
}

extern "C" void kernel_launch(void* const* d_in, const int* in_sizes, int n_in,
                              void* d_out, int out_size, void* d_ws, size_t ws_size,
                              hipStream_t stream) {
    const float* x    = (const float*)d_in[0];
    const float* offs = (const float*)d_in[1];
    const float* mask = (const float*)d_in[2];
    const float* w    = (const float*)d_in[3];
    const float* bias = (const float*)d_in[4];
    float* out = (float*)d_out;

    char* ws = (char*)d_ws;
    unsigned short* xn  = (unsigned short*)(ws);               // 8 MB bf16 NHWC
    unsigned short* wt2 = (unsigned short*)(ws + (8u << 20));  // 72 KB

    hipLaunchKernelGGL(prep, dim3(1168), dim3(256), 0, stream, x, w, xn, wt2);
    hipLaunchKernelGGL(dcn_main, dim3(4096), dim3(256), 0, stream,
                       xn, wt2, offs, mask, bias, out);
}

// Round 15
// 46.377 us; speedup vs baseline: 1.7602x; 1.2174x over previous
//
#include <hip/hip_runtime.h>

#define BATCH 4
#define CIN 64
#define H 128
#define W 128
#define COUT 64
#define KK 9
#define HO 128
#define WO 128

typedef short bf16x8 __attribute__((ext_vector_type(8)));
typedef float f32x4 __attribute__((ext_vector_type(4)));

__device__ __forceinline__ unsigned short f2bf(float f) {
    unsigned u = __builtin_bit_cast(unsigned, f);
    u += 0x7FFFu + ((u >> 16) & 1u);          // RNE
    return (unsigned short)(u >> 16);
}
__device__ __forceinline__ float bflo(unsigned u) {   // low bf16 of dword
    return __builtin_bit_cast(float, u << 16);
}
__device__ __forceinline__ float bfhi(unsigned u) {   // high bf16 of dword
    return __builtin_bit_cast(float, u & 0xFFFF0000u);
}

// bilinear on one packed dword-column (2 channels), pack result to bf16x2
__device__ __forceinline__ unsigned bil_pack(unsigned u0, unsigned u1,
                                             unsigned u2, unsigned u3, f32x4 wv) {
    float lo = fmaf(wv[0], bflo(u0), fmaf(wv[1], bflo(u1),
               fmaf(wv[2], bflo(u2), wv[3] * bflo(u3))));
    float hi = fmaf(wv[0], bfhi(u0), fmaf(wv[1], bfhi(u1),
               fmaf(wv[2], bfhi(u2), wv[3] * bfhi(u3))));
    unsigned pk;
    asm("v_cvt_pk_bf16_f32 %0, %1, %2" : "=v"(pk) : "v"(lo), "v"(hi));
    return pk;
}

// Fused prep:
//  blocks 0..1023   : (b,oy,xh) NCHW->NHWC bf16 transpose + 576 sample descriptors
//  blocks 1024..1167: weight transpose  w[COUT][CIN][3][3] -> wt2[o][k*64+c] bf16
__global__ __launch_bounds__(256)
void prep(const float* __restrict__ x, const float* __restrict__ offs,
          const float* __restrict__ mask, const float* __restrict__ w,
          unsigned short* __restrict__ xn, unsigned short* __restrict__ wt2,
          int* __restrict__ di, float* __restrict__ dw) {
    const int blk = blockIdx.x;
    const int tid = threadIdx.x;

    if (blk >= 1024) {
        int g = (blk - 1024) * 256 + tid;     // 0..36863
        int o = g / 576;
        int rem = g - o * 576;
        int k = rem >> 6, c = rem & 63;
        wt2[g] = f2bf(w[(o * 64 + c) * 9 + k]);
        return;
    }

    const int b = blk >> 8, oy = (blk >> 1) & 127, xh = blk & 1;

    // ---- NHWC bf16 transpose for this 64-px row-half ----
    __shared__ float T[64][65];
    {
        const int px = tid & 63, cq = tid >> 6;
        const float* src = x + (((size_t)b * 64) << 14) + oy * 128 + xh * 64;
        #pragma unroll
        for (int j = 0; j < 16; ++j) {
            int c = cq * 16 + j;
            T[c][px] = src[((size_t)c << 14) + px];
        }
        __syncthreads();
        const int c2 = tid & 63, pq = tid >> 6;
        unsigned short* dst = xn + ((((size_t)b << 14) + oy * 128 + xh * 64) << 6) + c2;
        #pragma unroll
        for (int j = 0; j < 16; ++j) {
            int p = pq * 16 + j;
            dst[(size_t)p << 6] = f2bf(T[c2][p]);
        }
    }

    // ---- descriptors: one lane per sample point ----
    const int gbase = blk * 576;
    #pragma unroll
    for (int i = 0; i < 3; ++i) {
        int s = i * 256 + tid;
        if (s < 576) {
            int k = s >> 6, spx = s & 63;
            int ox = xh * 64 + spx;
            int kh = k / 3, kw = k - kh * 3;

            float offy = offs[((b * 18 + 2 * k    ) * 128 + oy) * 128 + ox];
            float offx = offs[((b * 18 + 2 * k + 1) * 128 + oy) * 128 + ox];
            float m    = mask[((b * 9  + k        ) * 128 + oy) * 128 + ox];

            float py  = (float)(oy - 1 + kh) + offy;
            float pxf = (float)(ox - 1 + kw) + offx;
            float fy = floorf(py), fx = floorf(pxf);
            float ly = py - fy, lx = pxf - fx;
            int y0 = (int)fy, x0 = (int)fx;
            int y1 = y0 + 1, x1 = x0 + 1;

            bool y0v = (y0 >= 0) & (y0 < H), y1v = (y1 >= 0) & (y1 < H);
            bool x0v = (x0 >= 0) & (x0 < W), x1v = (x1 >= 0) & (x1 < W);
            int y0c = min(max(y0, 0), H-1), y1c = min(max(y1, 0), H-1);
            int x0c = min(max(x0, 0), W-1), x1c = min(max(x1, 0), W-1);

            int p00 = (b << 14) + y0c * 128 + x0c;            // fits 16 bits
            int dx = x1c - x0c, dy = y1c - y0c;
            di[gbase + s] = p00 | (dx << 16) | (dy << 17);

            f32x4 wv;
            wv[0] = (1.f - ly) * (1.f - lx) * m * ((y0v & x0v) ? 1.f : 0.f);
            wv[1] = (1.f - ly) * lx         * m * ((y0v & x1v) ? 1.f : 0.f);
            wv[2] = ly         * (1.f - lx) * m * ((y1v & x0v) ? 1.f : 0.f);
            wv[3] = ly         * lx         * m * ((y1v & x1v) ? 1.f : 0.f);
            *(f32x4*)(dw + (size_t)(gbase + s) * 4) = wv;
        }
    }
}

__global__ __launch_bounds__(256, 4)
void dcn_main(const unsigned short* __restrict__ xn, const unsigned short* __restrict__ wt2,
              const int* __restrict__ di, const float* __restrict__ dw,
              const float* __restrict__ bias, float* __restrict__ out) {
    const int tid  = threadIdx.x;
    const int lane = tid & 63;
    const int wid  = tid >> 6;
    const int bid  = blockIdx.x;            // 2048
    const int blk  = (bid & 7) * 256 + (bid >> 3);   // XCD swizzle (bijective)
    const int p    = blk & 1;               // 32-px phase
    const int xh   = (blk >> 1) & 1;
    const int oy   = (blk >> 2) & 127;
    const int b    = blk >> 9;
    const int bo   = blk >> 1;              // prep-block id (0..1023)

    const int lg = lane >> 3;               // sample-in-group 0..7
    const int lc = lane & 7;                // channel-slice (channels lc*8..+7)

    __shared__ __align__(16) unsigned short S[32 * 576];   // 36 KB swizzled [pxl][r]
    const uint4* x4 = (const uint4*)xn;     // 16B view: row = px*8 uint4s

    const int sbase = bo * 576 + p * 32;
    const int gi0   = wid * 9;              // this wave's 9 groups (8 samples each)

    // ---- gather: dwordx4-packed corners, parity-prefetched descriptors ----
    #define LOADDESC(GI, D, WV)                                            \
    {   int si = sbase + (((GI) >> 2) << 6) + (((GI) & 3) << 3) + lg;      \
        D  = di[si];                                                       \
        WV = *(const f32x4*)(dw + (size_t)si * 4);                         \
    }
    #define PROCESS(GI, D, WV)                                             \
    {   int k_  = (GI) >> 2;                                               \
        int pxl = (((GI) & 3) << 3) + lg;                                  \
        unsigned p00   = (unsigned)(D) & 0xFFFFu;                          \
        unsigned base4 = (p00 << 3) + (unsigned)lc;                        \
        unsigned o01   = (((unsigned)(D) >> 16) & 1u) << 3;                \
        unsigned o10   = (((unsigned)(D) >> 17) & 1u) << 10;               \
        uint4 c00 = x4[base4];                                             \
        uint4 c01 = x4[base4 + o01];                                       \
        uint4 c10 = x4[base4 + o10];                                       \
        uint4 c11 = x4[base4 + o01 + o10];                                 \
        uint4 pk;                                                          \
        pk.x = bil_pack(c00.x, c01.x, c10.x, c11.x, WV);                   \
        pk.y = bil_pack(c00.y, c01.y, c10.y, c11.y, WV);                   \
        pk.z = bil_pack(c00.z, c01.z, c10.z, c11.z, WV);                   \
        pk.w = bil_pack(c00.w, c01.w, c10.w, c11.w, WV);                   \
        int sb = pxl * 1152 + k_ * 128 + ((lc * 16) ^ ((pxl & 7) << 4));   \
        *(uint4*)((char*)S + sb) = pk;                                     \
    }

    int dA, dB; f32x4 wA, wB;
    LOADDESC(gi0, dA, wA)
    #pragma unroll 1
    for (int gg = 0; gg < 4; ++gg) {
        LOADDESC(gi0 + 2 * gg + 1, dB, wB)
        PROCESS(gi0 + 2 * gg, dA, wA)
        LOADDESC(gi0 + 2 * gg + 2, dA, wA)
        PROCESS(gi0 + 2 * gg + 1, dB, wB)
    }
    PROCESS(gi0 + 8, dA, wA)
    #undef PROCESS
    #undef LOADDESC
    __syncthreads();

    // ---- MFMA sweep, K = 576, afrag depth-1 prefetched from L2-hot wt2 ----
    f32x4 acc0 = {}, acc1 = {};
    {
        int o = wid * 16 + (lane & 15);
        const unsigned short* wp = wt2 + o * 576 + (lane >> 4) * 8;
        const int pxr0 = lane & 15;
        const int rb   = (lane >> 4) * 16;            // byte col base
        const int swz0 = (pxr0 & 7) << 4;
        const int bo0base = pxr0 * 1152;
        const int bo1base = (pxr0 + 16) * 1152;

        bf16x8 afA = *(const bf16x8*)(wp);
        bf16x8 afB;
        #pragma unroll 1
        for (int ss = 0; ss < 9; ++ss) {
            afB = *(const bf16x8*)(wp + (2 * ss + 1) * 32);
            {
                int colx = (2 * ss * 64 + rb) ^ swz0;
                bf16x8 b0 = *(const bf16x8*)((const char*)S + bo0base + colx);
                bf16x8 b1 = *(const bf16x8*)((const char*)S + bo1base + colx);
                acc0 = __builtin_amdgcn_mfma_f32_16x16x32_bf16(afA, b0, acc0, 0, 0, 0);
                acc1 = __builtin_amdgcn_mfma_f32_16x16x32_bf16(afA, b1, acc1, 0, 0, 0);
            }
            if (ss < 8) afA = *(const bf16x8*)(wp + (2 * ss + 2) * 32);
            {
                int colx = ((2 * ss + 1) * 64 + rb) ^ swz0;
                bf16x8 b0 = *(const bf16x8*)((const char*)S + bo0base + colx);
                bf16x8 b1 = *(const bf16x8*)((const char*)S + bo1base + colx);
                acc0 = __builtin_amdgcn_mfma_f32_16x16x32_bf16(afB, b0, acc0, 0, 0, 0);
                acc1 = __builtin_amdgcn_mfma_f32_16x16x32_bf16(afB, b1, acc1, 0, 0, 0);
            }
        }
    }

    // ---- epilogue for this block's 32 pixels ----
    const int q0 = (lane >> 4) * 4;
    #pragma unroll
    for (int q = 0; q < 4; ++q) {
        int o   = wid * 16 + q0 + q;
        int oxb = xh * 64 + p * 32 + (lane & 15);
        float* dst = out + (((size_t)(b * 64 + o)) * 128 + oy) * 128 + oxb;
        dst[0]  = acc0[q] + bias[o];
        dst[16] = acc1[q] + bias[o];
    }
}

extern "C" void kernel_launch(void* const* d_in, const int* in_sizes, int n_in,
                              void* d_out, int out_size, void* d_ws, size_t ws_size,
                              hipStream_t stream) {
    const float* x    = (const float*)d_in[0];
    const float* offs = (const float*)d_in[1];
    const float* mask = (const float*)d_in[2];
    const float* w    = (const float*)d_in[3];
    const float* bias = (const float*)d_in[4];
    float* out = (float*)d_out;

    // workspace layout
    char* ws = (char*)d_ws;
    unsigned short* xn  = (unsigned short*)(ws);                   //  8 MB  (bf16 NHWC)
    unsigned short* wt2 = (unsigned short*)(ws + (8u  << 20));     // 72 KB
    int*            di  = (int*)           (ws + (9u  << 20));     // ~2.4 MB
    float*          dw  = (float*)         (ws + (12u << 20));     // ~9.5 MB

    hipLaunchKernelGGL(prep, dim3(1168), dim3(256), 0, stream,
                       x, offs, mask, w, xn, wt2, di, dw);
    hipLaunchKernelGGL(dcn_main, dim3(2048), dim3(256), 0, stream,
                       xn, wt2, di, dw, bias, out);
}